// Round 3
// baseline (279.475 us; speedup 1.0000x reference)
//
#include <hip/hip_runtime.h>

#define GROUPS 32
#define EPS 1e-5f

typedef unsigned short u16;
typedef __bf16 bf16x8 __attribute__((ext_vector_type(8)));
typedef float f32x4 __attribute__((ext_vector_type(4)));

__device__ __forceinline__ u16 f2bf(float f) {
  unsigned x = __builtin_bit_cast(unsigned, f);
  x += 0x7FFFu + ((x >> 16) & 1u);
  return (u16)(x >> 16);
}
__device__ __forceinline__ float bf2f(u16 u) {
  unsigned x = ((unsigned)u) << 16;
  return __builtin_bit_cast(float, x);
}

__device__ __forceinline__ void gload_lds16(const void* g, void* l) {
  __builtin_amdgcn_global_load_lds(
      (const __attribute__((address_space(1))) void*)g,
      (__attribute__((address_space(3))) void*)l, 16, 0, 0);
}

// ---------------- weight fp32 -> bf16 (all 4 weights, one dispatch) --------
__global__ __launch_bounds__(256) void cvt_kernel(
    const float* __restrict__ wq, const float* __restrict__ wk,
    const float* __restrict__ wv, const float* __restrict__ wo,
    u16* __restrict__ Wqk, u16* __restrict__ Wv, u16* __restrict__ Wo,
    int n) {
  int i = (blockIdx.x * 256 + threadIdx.x) * 4;
  if (i >= n) return;
  const float* src;
  u16* dst;
  switch (blockIdx.y) {
    case 0: src = wq; dst = Wqk; break;
    case 1: src = wk; dst = Wqk + n; break;
    case 2: src = wv; dst = Wv; break;
    default: src = wo; dst = Wo; break;
  }
  float4 v = *(const float4*)&src[i];
  ushort4 o;
  o.x = f2bf(v.x); o.y = f2bf(v.y); o.z = f2bf(v.z); o.w = f2bf(v.w);
  *(ushort4*)&dst[i] = o;
}

// ---------------- bias concat bq||bk -> fp32[1024] ----------------
__global__ __launch_bounds__(256) void biascat_kernel(
    const float* __restrict__ bq, const float* __restrict__ bk,
    float* __restrict__ bqk, int C) {
  int i = blockIdx.x * 256 + threadIdx.x;
  if (i < C) bqk[i] = bq[i];
  else if (i < 2 * C) bqk[i] = bk[i - C];
}

// ---------------- GroupNorm -> HT [N, S, C] bf16 ----------------
__global__ __launch_bounds__(256) void groupnorm_kernel(
    const float* __restrict__ x, const float* __restrict__ gamma,
    const float* __restrict__ beta, u16* __restrict__ HT, int C, int S) {
  const int cpg = C / GROUPS;  // 16
  int n = blockIdx.x / GROUPS;
  int g = blockIdx.x % GROUPS;
  const float* xb = x + ((size_t)n * C + (size_t)g * cpg) * S;
  int tid = threadIdx.x;
  int cnt = cpg * S;  // 16384
  float s = 0.f, ss = 0.f;
  for (int i = tid * 4; i < cnt; i += 256 * 4) {
    float4 v = *(const float4*)&xb[i];
    s += v.x + v.y + v.z + v.w;
    ss += v.x * v.x + v.y * v.y + v.z * v.z + v.w * v.w;
  }
  for (int o = 32; o > 0; o >>= 1) {
    s += __shfl_xor(s, o);
    ss += __shfl_xor(ss, o);
  }
  __shared__ float rs[4], rss[4];
  int wave = tid >> 6, lane = tid & 63;
  if (lane == 0) { rs[wave] = s; rss[wave] = ss; }
  __syncthreads();
  float S1 = rs[0] + rs[1] + rs[2] + rs[3];
  float S2 = rss[0] + rss[1] + rss[2] + rss[3];
  float mean = S1 / (float)cnt;
  float var = S2 / (float)cnt - mean * mean;
  float rstd = rsqrtf(var + EPS);
  float gm[16], bt[16];
#pragma unroll
  for (int c = 0; c < 16; ++c) {
    float gmv = gamma[g * cpg + c] * rstd;
    gm[c] = gmv;
    bt[c] = beta[g * cpg + c] - mean * gmv;
  }
  for (int i = 0; i < S; i += 256) {
    int sp = i + tid;
    u16 outv[16];
#pragma unroll
    for (int c = 0; c < 16; ++c) {
      float h = xb[(size_t)c * S + sp] * gm[c] + bt[c];
      outv[c] = f2bf(h);
    }
    u16* dst = HT + ((size_t)n * S + sp) * C + g * cpg;
    *(int4*)dst = *(int4*)&outv[0];
    *(int4*)&dst[8] = *(int4*)&outv[8];
  }
}

// =================== 256x256x64 8-phase GEMM (8 waves) =====================
// Out[m][n] = scale*sum_k A[m][k]*B[n][k] (+bias/residual)
// LDS: ring of 4 k-half slots per operand ([256][32] bf16 each, 16KB).
//   slot(kt,kh) = (2*kt+kh)&3. Tile kt computes kh0 in phases 0-1, kh1 in 2-3.
// Stage schedule (1 half-tile = 2 gload_lds per phase, into slot freed at the
//   preceding barrier): p0: A-kh1(kt+1), p1: B-kh1(kt+1), p2: A-kh0(kt+2),
//   p3: B-kh0(kt+2). Gate: vmcnt(4) at p3 only (2 half-tiles in flight) --
//   all 4 halves of tile kt+1 are then landed before its phase 0.
// Swizzle: 16B slot within 64B row ^= (row>>1)&3 on both global source and
//   ds_read (2-way banks = free). XCD-bijective block swizzle.
__global__ __launch_bounds__(512, 2) void gemm256_kernel(
    const u16* __restrict__ A, long lda, long strideA,
    const u16* __restrict__ B, long ldb, long strideB,
    void* __restrict__ Out, long ldo, long strideO, int out_fp32,
    const float* __restrict__ bias, int bias_mode,  // 0 none, 1 row, 2 col
    float scale, const float* __restrict__ residual, int K, int nbx, int nby) {
  __shared__ u16 lds[65536];  // 128 KiB
  u16* As = lds;
  u16* Bs = lds + 32768;

  int tid = threadIdx.x;
  int wave = tid >> 6, lane = tid & 63;
  int wr = wave >> 2, wc = wave & 3;
  int l15 = lane & 15, l4 = lane >> 4;

  int nwg = gridDim.x;
  int orig = blockIdx.x;
  int swz = ((nwg & 7) == 0) ? (orig & 7) * (nwg >> 3) + (orig >> 3) : orig;
  int tilesPB = nbx * nby;
  int z = swz / tilesPB, rem = swz % tilesPB;
  int bx = rem % nbx, by = rem / nbx;

  const u16* Ab = A + (long)z * strideA + (long)by * 256 * lda;
  const u16* Bb = B + (long)z * strideB + (long)bx * 256 * ldb;

  auto STAGE = [&](const u16* Gb, long ld, int kt, int kh, u16* ops) {
    u16* sb = ops + ((2 * kt + kh) & 3) * 8192;
#pragma unroll
    for (int i = 0; i < 2; ++i) {
      int c = i * 512 + tid;
      int row = c >> 2, sl = c & 3;
      int ssl = sl ^ ((row >> 1) & 3);
      gload_lds16(Gb + (long)row * ld + kt * 64 + kh * 32 + ssl * 8,
                  sb + (i * 512 + wave * 64) * 8);
    }
  };
  auto LDA_ = [&](int slot, int m) -> bf16x8 {
    int row = wr * 128 + m * 16 + l15;
    int sl = l4 ^ ((row >> 1) & 3);
    return *(const bf16x8*)&As[slot * 8192 + row * 32 + sl * 8];
  };
  auto LDB_ = [&](int slot, int n) -> bf16x8 {
    int row = wc * 64 + n * 16 + l15;
    int sl = l4 ^ ((row >> 1) & 3);
    return *(const bf16x8*)&Bs[slot * 8192 + row * 32 + sl * 8];
  };

  f32x4 acc[8][4] = {};
  int NT = K >> 6;

  // prologue: tile0 all 4 halves + tile1 kh0 (12 loads)
  STAGE(Ab, lda, 0, 0, As); STAGE(Bb, ldb, 0, 0, Bs);
  STAGE(Ab, lda, 0, 1, As); STAGE(Bb, ldb, 0, 1, Bs);
  STAGE(Ab, lda, 1, 0, As); STAGE(Bb, ldb, 1, 0, Bs);
  asm volatile("s_waitcnt vmcnt(4)" ::: "memory");  // tile0 landed
  __builtin_amdgcn_sched_barrier(0);
  __builtin_amdgcn_s_barrier();
  __builtin_amdgcn_sched_barrier(0);

#pragma unroll 2
  for (int kt = 0; kt < NT; ++kt) {
    int s0 = (2 * kt) & 3, s1 = (2 * kt + 1) & 3;
    bf16x8 af[8], bf0, bf1;

    // ---- phase 0: kh0 x n{0,1}; stage A-kh1(kt+1)
#pragma unroll
    for (int m = 0; m < 8; ++m) af[m] = LDA_(s0, m);
    bf0 = LDB_(s0, 0); bf1 = LDB_(s0, 1);
    if (kt + 1 < NT) STAGE(Ab, lda, kt + 1, 1, As);
    __builtin_amdgcn_s_barrier();
    __builtin_amdgcn_s_setprio(1);
#pragma unroll
    for (int m = 0; m < 8; ++m) {
      acc[m][0] = __builtin_amdgcn_mfma_f32_16x16x32_bf16(af[m], bf0, acc[m][0], 0, 0, 0);
      acc[m][1] = __builtin_amdgcn_mfma_f32_16x16x32_bf16(af[m], bf1, acc[m][1], 0, 0, 0);
    }
    __builtin_amdgcn_s_setprio(0);
    __builtin_amdgcn_s_barrier();

    // ---- phase 1: kh0 x n{2,3}; stage B-kh1(kt+1)
    bf0 = LDB_(s0, 2); bf1 = LDB_(s0, 3);
    if (kt + 1 < NT) STAGE(Bb, ldb, kt + 1, 1, Bs);
    __builtin_amdgcn_s_barrier();
    __builtin_amdgcn_s_setprio(1);
#pragma unroll
    for (int m = 0; m < 8; ++m) {
      acc[m][2] = __builtin_amdgcn_mfma_f32_16x16x32_bf16(af[m], bf0, acc[m][2], 0, 0, 0);
      acc[m][3] = __builtin_amdgcn_mfma_f32_16x16x32_bf16(af[m], bf1, acc[m][3], 0, 0, 0);
    }
    __builtin_amdgcn_s_setprio(0);
    __builtin_amdgcn_s_barrier();

    // ---- phase 2: kh1 x n{0,1}; stage A-kh0(kt+2)
#pragma unroll
    for (int m = 0; m < 8; ++m) af[m] = LDA_(s1, m);
    bf0 = LDB_(s1, 0); bf1 = LDB_(s1, 1);
    if (kt + 2 < NT) STAGE(Ab, lda, kt + 2, 0, As);
    __builtin_amdgcn_s_barrier();
    __builtin_amdgcn_s_setprio(1);
#pragma unroll
    for (int m = 0; m < 8; ++m) {
      acc[m][0] = __builtin_amdgcn_mfma_f32_16x16x32_bf16(af[m], bf0, acc[m][0], 0, 0, 0);
      acc[m][1] = __builtin_amdgcn_mfma_f32_16x16x32_bf16(af[m], bf1, acc[m][1], 0, 0, 0);
    }
    __builtin_amdgcn_s_setprio(0);
    __builtin_amdgcn_s_barrier();

    // ---- phase 3: kh1 x n{2,3}; stage B-kh0(kt+2); vmcnt gate
    bf0 = LDB_(s1, 2); bf1 = LDB_(s1, 3);
    if (kt + 2 < NT) STAGE(Bb, ldb, kt + 2, 0, Bs);
    __builtin_amdgcn_s_barrier();
    __builtin_amdgcn_s_setprio(1);
#pragma unroll
    for (int m = 0; m < 8; ++m) {
      acc[m][2] = __builtin_amdgcn_mfma_f32_16x16x32_bf16(af[m], bf0, acc[m][2], 0, 0, 0);
      acc[m][3] = __builtin_amdgcn_mfma_f32_16x16x32_bf16(af[m], bf1, acc[m][3], 0, 0, 0);
    }
    __builtin_amdgcn_s_setprio(0);
    asm volatile("s_waitcnt vmcnt(4)" ::: "memory");  // tile kt+1 fully landed
    __builtin_amdgcn_sched_barrier(0);
    __builtin_amdgcn_s_barrier();
    __builtin_amdgcn_sched_barrier(0);
  }

  long orow0 = (long)by * 256 + wr * 128;
  long ocol0 = (long)bx * 256 + wc * 64;
#pragma unroll
  for (int m = 0; m < 8; ++m) {
#pragma unroll
    for (int n = 0; n < 4; ++n) {
#pragma unroll
      for (int r = 0; r < 4; ++r) {
        long row = orow0 + m * 16 + l4 * 4 + r;
        long col = ocol0 + n * 16 + l15;
        float v = acc[m][n][r] * scale;
        if (bias_mode == 1) v += bias[row];
        else if (bias_mode == 2) v += bias[col];
        long off = (long)z * strideO + row * ldo + col;
        if (residual) v += residual[off];
        if (out_fp32) ((float*)Out)[off] = v;
        else ((u16*)Out)[off] = f2bf(v);
      }
    }
  }
}

// ---------------- softmax over rows of P [rows, S] bf16, in place ----------
__global__ __launch_bounds__(256) void softmax_kernel(u16* __restrict__ P, int S) {
  size_t row = blockIdx.x;
  u16* p = P + row * (size_t)S;
  int tid = threadIdx.x;
  ushort4 u = *(const ushort4*)&p[tid * 4];
  float v0 = bf2f(u.x), v1 = bf2f(u.y), v2 = bf2f(u.z), v3 = bf2f(u.w);
  float m = fmaxf(fmaxf(v0, v1), fmaxf(v2, v3));
  for (int o = 32; o > 0; o >>= 1) m = fmaxf(m, __shfl_xor(m, o));
  __shared__ float redm[4], reds[4];
  int wave = tid >> 6, lane = tid & 63;
  if (lane == 0) redm[wave] = m;
  __syncthreads();
  m = fmaxf(fmaxf(redm[0], redm[1]), fmaxf(redm[2], redm[3]));
  float e0 = __expf(v0 - m), e1 = __expf(v1 - m);
  float e2 = __expf(v2 - m), e3 = __expf(v3 - m);
  float s = e0 + e1 + e2 + e3;
  for (int o = 32; o > 0; o >>= 1) s += __shfl_xor(s, o);
  if (lane == 0) reds[wave] = s;
  __syncthreads();
  s = reds[0] + reds[1] + reds[2] + reds[3];
  float inv = 1.f / s;
  ushort4 o4;
  o4.x = f2bf(e0 * inv); o4.y = f2bf(e1 * inv);
  o4.z = f2bf(e2 * inv); o4.w = f2bf(e3 * inv);
  *(ushort4*)&p[tid * 4] = o4;
}

extern "C" void kernel_launch(void* const* d_in, const int* in_sizes, int n_in,
                              void* d_out, int out_size, void* d_ws, size_t ws_size,
                              hipStream_t stream) {
  const float* x = (const float*)d_in[0];
  const float* gamma = (const float*)d_in[1];
  const float* beta = (const float*)d_in[2];
  const float* wq = (const float*)d_in[3];
  const float* bq = (const float*)d_in[4];
  const float* wk = (const float*)d_in[5];
  const float* bk = (const float*)d_in[6];
  const float* wv = (const float*)d_in[7];
  const float* bv = (const float*)d_in[8];
  const float* wo = (const float*)d_in[9];
  const float* bo = (const float*)d_in[10];

  const int C = 512, S = 1024;
  const int N = in_sizes[0] / (C * S);  // 16
  const long SC = (long)S * C;
  const long S2C = (long)S * 2 * C;
  const long SS = (long)S * S;
  const int CC = C * C;

  char* ws = (char*)d_ws;
  const size_t MB = 1024 * 1024;
  u16* HT = (u16*)(ws + 0 * MB);      // [N,S,C]
  u16* QKT = (u16*)(ws + 16 * MB);    // [N,S,2C]: cols 0..C-1 = Q, C..2C-1 = K
  u16* Vb = (u16*)(ws + 48 * MB);     // [N,C,S]
  u16* P = (u16*)(ws + 64 * MB);      // [N,S,S]
  u16* Wqk = (u16*)(ws + 96 * MB);    // [2C,C]
  u16* Wv = Wqk + 2 * CC;
  u16* Wo = Wv + CC;
  float* bqk = (float*)(Wo + CC);     // [2C]
  u16* H2T = HT;                      // overlay: HT dead after V-GEMM

  cvt_kernel<<<dim3(CC / 1024, 4), 256, 0, stream>>>(wq, wk, wv, wo, Wqk, Wv, Wo, CC);
  biascat_kernel<<<4, 256, 0, stream>>>(bq, bk, bqk, C);
  groupnorm_kernel<<<N * GROUPS, 256, 0, stream>>>(x, gamma, beta, HT, C, S);

  const float scl = 1.0f / sqrtf((float)C);

  // fused Q,K projection: QKT[s][j] = sum_c HT[s][c]*Wqk[j][c] + bqk[j]
  gemm256_kernel<<<dim3((2 * C / 256) * (S / 256) * N), 512, 0, stream>>>(
      HT, C, SC, Wqk, C, 0, QKT, 2 * C, S2C, 0, bqk, 2, 1.f, nullptr, C,
      2 * C / 256, S / 256);
  // V[c][s] = sum_k Wv[c][k]*HT[s][k] + bv[c]
  gemm256_kernel<<<dim3((S / 256) * (C / 256) * N), 512, 0, stream>>>(
      Wv, C, 0, HT, C, SC, Vb, S, SC, 0, bv, 1, 1.f, nullptr, C,
      S / 256, C / 256);
  // P[s][t] = scl * sum_c Q[s][c]*K[t][c]
  gemm256_kernel<<<dim3((S / 256) * (S / 256) * N), 512, 0, stream>>>(
      QKT, 2 * C, S2C, QKT + C, 2 * C, S2C, P, S, SS, 0, nullptr, 0, scl,
      nullptr, C, S / 256, S / 256);
  softmax_kernel<<<N * S, 256, 0, stream>>>(P, S);
  // H2T[s][c] = sum_t P[s][t]*V[c][t]
  gemm256_kernel<<<dim3((C / 256) * (S / 256) * N), 512, 0, stream>>>(
      P, S, SS, Vb, S, SC, H2T, C, SC, 0, nullptr, 0, 1.f, nullptr, S,
      C / 256, S / 256);
  // out[c][s] = x + bo[c] + sum_k Wo[c][k]*H2T[s][k]   (fp32)
  gemm256_kernel<<<dim3((S / 256) * (C / 256) * N), 512, 0, stream>>>(
      Wo, C, 0, H2T, C, SC, d_out, S, SC, 1, bo, 1, 1.f, x, C,
      S / 256, C / 256);
}

// Round 4
// 272.863 us; speedup vs baseline: 1.0242x; 1.0242x over previous
//
#include <hip/hip_runtime.h>

#define GROUPS 32
#define EPS 1e-5f

typedef unsigned short u16;
typedef __bf16 bf16x8 __attribute__((ext_vector_type(8)));
typedef float f32x4 __attribute__((ext_vector_type(4)));

__device__ __forceinline__ u16 f2bf(float f) {
  unsigned x = __builtin_bit_cast(unsigned, f);
  x += 0x7FFFu + ((x >> 16) & 1u);
  return (u16)(x >> 16);
}
__device__ __forceinline__ float bf2f(u16 u) {
  unsigned x = ((unsigned)u) << 16;
  return __builtin_bit_cast(float, x);
}

__device__ __forceinline__ void gload_lds16(const void* g, void* l) {
  __builtin_amdgcn_global_load_lds(
      (const __attribute__((address_space(1))) void*)g,
      (__attribute__((address_space(3))) void*)l, 16, 0, 0);
}

// ---------------- weight fp32 -> bf16 (all 4 weights, one dispatch) --------
__global__ __launch_bounds__(256) void cvt_kernel(
    const float* __restrict__ wq, const float* __restrict__ wk,
    const float* __restrict__ wv, const float* __restrict__ wo,
    u16* __restrict__ Wqk, u16* __restrict__ Wv, u16* __restrict__ Wo,
    int n) {
  int i = (blockIdx.x * 256 + threadIdx.x) * 4;
  if (i >= n) return;
  const float* src;
  u16* dst;
  switch (blockIdx.y) {
    case 0: src = wq; dst = Wqk; break;
    case 1: src = wk; dst = Wqk + n; break;
    case 2: src = wv; dst = Wv; break;
    default: src = wo; dst = Wo; break;
  }
  float4 v = *(const float4*)&src[i];
  ushort4 o;
  o.x = f2bf(v.x); o.y = f2bf(v.y); o.z = f2bf(v.z); o.w = f2bf(v.w);
  *(ushort4*)&dst[i] = o;
}

// ---------------- bias concat bq||bk -> fp32[1024] ----------------
__global__ __launch_bounds__(256) void biascat_kernel(
    const float* __restrict__ bq, const float* __restrict__ bk,
    float* __restrict__ bqk, int C) {
  int i = blockIdx.x * 256 + threadIdx.x;
  if (i < C) bqk[i] = bq[i];
  else if (i < 2 * C) bqk[i] = bk[i - C];
}

// ---------------- GroupNorm -> HT [N, S, C] bf16 ----------------
__global__ __launch_bounds__(256) void groupnorm_kernel(
    const float* __restrict__ x, const float* __restrict__ gamma,
    const float* __restrict__ beta, u16* __restrict__ HT, int C, int S) {
  const int cpg = C / GROUPS;  // 16
  int n = blockIdx.x / GROUPS;
  int g = blockIdx.x % GROUPS;
  const float* xb = x + ((size_t)n * C + (size_t)g * cpg) * S;
  int tid = threadIdx.x;
  int cnt = cpg * S;  // 16384
  float s = 0.f, ss = 0.f;
  for (int i = tid * 4; i < cnt; i += 256 * 4) {
    float4 v = *(const float4*)&xb[i];
    s += v.x + v.y + v.z + v.w;
    ss += v.x * v.x + v.y * v.y + v.z * v.z + v.w * v.w;
  }
  for (int o = 32; o > 0; o >>= 1) {
    s += __shfl_xor(s, o);
    ss += __shfl_xor(ss, o);
  }
  __shared__ float rs[4], rss[4];
  int wave = tid >> 6, lane = tid & 63;
  if (lane == 0) { rs[wave] = s; rss[wave] = ss; }
  __syncthreads();
  float S1 = rs[0] + rs[1] + rs[2] + rs[3];
  float S2 = rss[0] + rss[1] + rss[2] + rss[3];
  float mean = S1 / (float)cnt;
  float var = S2 / (float)cnt - mean * mean;
  float rstd = rsqrtf(var + EPS);
  float gm[16], bt[16];
#pragma unroll
  for (int c = 0; c < 16; ++c) {
    float gmv = gamma[g * cpg + c] * rstd;
    gm[c] = gmv;
    bt[c] = beta[g * cpg + c] - mean * gmv;
  }
  for (int i = 0; i < S; i += 256) {
    int sp = i + tid;
    u16 outv[16];
#pragma unroll
    for (int c = 0; c < 16; ++c) {
      float h = xb[(size_t)c * S + sp] * gm[c] + bt[c];
      outv[c] = f2bf(h);
    }
    u16* dst = HT + ((size_t)n * S + sp) * C + g * cpg;
    *(int4*)dst = *(int4*)&outv[0];
    *(int4*)&dst[8] = *(int4*)&outv[8];
  }
}

// =================== 256x256x64 2-phase GEMM (8 waves) =====================
// Out[m][n] = scale*sum_k A[m][k]*B[n][k] (+bias/residual)
// m230-template: per K-tile { STAGE(next buf) issued FIRST; compute current
// (2 k-halves x 32 MFMA); vmcnt(0); s_barrier }. Double-buffered LDS 128KB.
// Row = 64 bf16 = 8 x 16B slots; physical slot p holds global slot p^(row&7)
// (pre-swizzled source + swizzled ds_read -> 2-way banks, free).
__global__ __launch_bounds__(512, 2) void gemm256_kernel(
    const u16* __restrict__ A, long lda, long strideA,
    const u16* __restrict__ B, long ldb, long strideB,
    void* __restrict__ Out, long ldo, long strideO, int out_fp32,
    const float* __restrict__ bias, int bias_mode,  // 0 none, 1 row, 2 col
    float scale, const float* __restrict__ residual, int K, int nbx, int nby) {
  __shared__ u16 lds[65536];  // 128 KiB
  u16* As0 = lds;
  u16* As1 = lds + 16384;
  u16* Bs0 = lds + 32768;
  u16* Bs1 = lds + 49152;

  int tid = threadIdx.x;
  int wave = tid >> 6, lane = tid & 63;
  int wr = wave >> 2, wc = wave & 3;
  int l15 = lane & 15, l4 = lane >> 4;

  int nwg = gridDim.x;
  int orig = blockIdx.x;
  int swz = ((nwg & 7) == 0) ? (orig & 7) * (nwg >> 3) + (orig >> 3) : orig;
  int tilesPB = nbx * nby;
  int z = swz / tilesPB, rem = swz % tilesPB;
  int bx = rem % nbx, by = rem / nbx;

  const u16* Ab = A + (long)z * strideA + (long)by * 256 * lda;
  const u16* Bb = B + (long)z * strideB + (long)bx * 256 * ldb;

  // stage one 256x64 tile of A and B each into (Ad, Bd)
  auto STAGE = [&](u16* Ad, u16* Bd, int kt) {
#pragma unroll
    for (int i = 0; i < 4; ++i) {
      int c = i * 512 + tid;          // 0..2047 16B chunks
      int row = c >> 3, p = c & 7;
      int gsl = p ^ (row & 7);        // inverse swizzle on global source
      long koff = (long)kt * 64 + gsl * 8;
      int lbase = (i * 512 + wave * 64) * 8;  // wave-uniform LDS base (elems)
      gload_lds16(Ab + (long)row * lda + koff, Ad + lbase);
      gload_lds16(Bb + (long)row * ldb + koff, Bd + lbase);
    }
  };

  f32x4 acc[8][4] = {};

  auto COMPUTE = [&](const u16* Asrc, const u16* Bsrc) {
#pragma unroll
    for (int kh = 0; kh < 2; ++kh) {
      bf16x8 af[8], bfr[4];
#pragma unroll
      for (int m = 0; m < 8; ++m) {
        int row = wr * 128 + m * 16 + l15;
        int p = (kh * 4 + l4) ^ (row & 7);
        af[m] = *(const bf16x8*)&Asrc[row * 64 + p * 8];
      }
#pragma unroll
      for (int n = 0; n < 4; ++n) {
        int row = wc * 64 + n * 16 + l15;
        int p = (kh * 4 + l4) ^ (row & 7);
        bfr[n] = *(const bf16x8*)&Bsrc[row * 64 + p * 8];
      }
#pragma unroll
      for (int m = 0; m < 8; ++m)
#pragma unroll
        for (int n = 0; n < 4; ++n)
          acc[m][n] = __builtin_amdgcn_mfma_f32_16x16x32_bf16(
              af[m], bfr[n], acc[m][n], 0, 0, 0);
    }
  };

  int NT = K >> 6;
  u16 *Ar = As0, *Br = Bs0, *Aw = As1, *Bw = Bs1;

  STAGE(Ar, Br, 0);
  asm volatile("s_waitcnt vmcnt(0)" ::: "memory");
  __builtin_amdgcn_sched_barrier(0);
  __builtin_amdgcn_s_barrier();
  __builtin_amdgcn_sched_barrier(0);

  for (int t = 0; t < NT - 1; ++t) {
    STAGE(Aw, Bw, t + 1);       // issue next-tile loads first
    COMPUTE(Ar, Br);            // they fly under ds_read + MFMA
    asm volatile("s_waitcnt vmcnt(0)" ::: "memory");
    __builtin_amdgcn_sched_barrier(0);
    __builtin_amdgcn_s_barrier();
    __builtin_amdgcn_sched_barrier(0);
    u16* tp;
    tp = Ar; Ar = Aw; Aw = tp;
    tp = Br; Br = Bw; Bw = tp;
  }
  COMPUTE(Ar, Br);

  long orow0 = (long)by * 256 + wr * 128;
  long ocol0 = (long)bx * 256 + wc * 64;
#pragma unroll
  for (int m = 0; m < 8; ++m) {
#pragma unroll
    for (int n = 0; n < 4; ++n) {
#pragma unroll
      for (int r = 0; r < 4; ++r) {
        long row = orow0 + m * 16 + l4 * 4 + r;
        long col = ocol0 + n * 16 + l15;
        float v = acc[m][n][r] * scale;
        if (bias_mode == 1) v += bias[row];
        else if (bias_mode == 2) v += bias[col];
        long off = (long)z * strideO + row * ldo + col;
        if (residual) v += residual[off];
        if (out_fp32) ((float*)Out)[off] = v;
        else ((u16*)Out)[off] = f2bf(v);
      }
    }
  }
}

// ---------------- softmax over rows of P [rows, S] bf16, in place ----------
__global__ __launch_bounds__(256) void softmax_kernel(u16* __restrict__ P, int S) {
  size_t row = blockIdx.x;
  u16* p = P + row * (size_t)S;
  int tid = threadIdx.x;
  ushort4 u = *(const ushort4*)&p[tid * 4];
  float v0 = bf2f(u.x), v1 = bf2f(u.y), v2 = bf2f(u.z), v3 = bf2f(u.w);
  float m = fmaxf(fmaxf(v0, v1), fmaxf(v2, v3));
  for (int o = 32; o > 0; o >>= 1) m = fmaxf(m, __shfl_xor(m, o));
  __shared__ float redm[4], reds[4];
  int wave = tid >> 6, lane = tid & 63;
  if (lane == 0) redm[wave] = m;
  __syncthreads();
  m = fmaxf(fmaxf(redm[0], redm[1]), fmaxf(redm[2], redm[3]));
  float e0 = __expf(v0 - m), e1 = __expf(v1 - m);
  float e2 = __expf(v2 - m), e3 = __expf(v3 - m);
  float s = e0 + e1 + e2 + e3;
  for (int o = 32; o > 0; o >>= 1) s += __shfl_xor(s, o);
  if (lane == 0) reds[wave] = s;
  __syncthreads();
  s = reds[0] + reds[1] + reds[2] + reds[3];
  float inv = 1.f / s;
  ushort4 o4;
  o4.x = f2bf(e0 * inv); o4.y = f2bf(e1 * inv);
  o4.z = f2bf(e2 * inv); o4.w = f2bf(e3 * inv);
  *(ushort4*)&p[tid * 4] = o4;
}

extern "C" void kernel_launch(void* const* d_in, const int* in_sizes, int n_in,
                              void* d_out, int out_size, void* d_ws, size_t ws_size,
                              hipStream_t stream) {
  const float* x = (const float*)d_in[0];
  const float* gamma = (const float*)d_in[1];
  const float* beta = (const float*)d_in[2];
  const float* wq = (const float*)d_in[3];
  const float* bq = (const float*)d_in[4];
  const float* wk = (const float*)d_in[5];
  const float* bk = (const float*)d_in[6];
  const float* wv = (const float*)d_in[7];
  const float* bv = (const float*)d_in[8];
  const float* wo = (const float*)d_in[9];
  const float* bo = (const float*)d_in[10];

  const int C = 512, S = 1024;
  const int N = in_sizes[0] / (C * S);  // 16
  const long SC = (long)S * C;
  const long S2C = (long)S * 2 * C;
  const long SS = (long)S * S;
  const int CC = C * C;

  char* ws = (char*)d_ws;
  const size_t MB = 1024 * 1024;
  u16* HT = (u16*)(ws + 0 * MB);      // [N,S,C]
  u16* QKT = (u16*)(ws + 16 * MB);    // [N,S,2C]: cols 0..C-1 = Q, C..2C-1 = K
  u16* Vb = (u16*)(ws + 48 * MB);     // [N,C,S]
  u16* P = (u16*)(ws + 64 * MB);      // [N,S,S]
  u16* Wqk = (u16*)(ws + 96 * MB);    // [2C,C]
  u16* Wv = Wqk + 2 * CC;
  u16* Wo = Wv + CC;
  float* bqk = (float*)(Wo + CC);     // [2C]
  u16* H2T = HT;                      // overlay: HT dead after V-GEMM

  cvt_kernel<<<dim3(CC / 1024, 4), 256, 0, stream>>>(wq, wk, wv, wo, Wqk, Wv, Wo, CC);
  biascat_kernel<<<4, 256, 0, stream>>>(bq, bk, bqk, C);
  groupnorm_kernel<<<N * GROUPS, 256, 0, stream>>>(x, gamma, beta, HT, C, S);

  const float scl = 1.0f / sqrtf((float)C);

  // fused Q,K projection: QKT[s][j] = sum_c HT[s][c]*Wqk[j][c] + bqk[j]
  gemm256_kernel<<<dim3((2 * C / 256) * (S / 256) * N), 512, 0, stream>>>(
      HT, C, SC, Wqk, C, 0, QKT, 2 * C, S2C, 0, bqk, 2, 1.f, nullptr, C,
      2 * C / 256, S / 256);
  // V[c][s] = sum_k Wv[c][k]*HT[s][k] + bv[c]
  gemm256_kernel<<<dim3((S / 256) * (C / 256) * N), 512, 0, stream>>>(
      Wv, C, 0, HT, C, SC, Vb, S, SC, 0, bv, 1, 1.f, nullptr, C,
      S / 256, C / 256);
  // P[s][t] = scl * sum_c Q[s][c]*K[t][c]
  gemm256_kernel<<<dim3((S / 256) * (S / 256) * N), 512, 0, stream>>>(
      QKT, 2 * C, S2C, QKT + C, 2 * C, S2C, P, S, SS, 0, nullptr, 0, scl,
      nullptr, C, S / 256, S / 256);
  softmax_kernel<<<N * S, 256, 0, stream>>>(P, S);
  // H2T[s][c] = sum_t P[s][t]*V[c][t]
  gemm256_kernel<<<dim3((C / 256) * (S / 256) * N), 512, 0, stream>>>(
      P, S, SS, Vb, S, SC, H2T, C, SC, 0, nullptr, 0, 1.f, nullptr, S,
      C / 256, S / 256);
  // out[c][s] = x + bo[c] + sum_k Wo[c][k]*H2T[s][k]   (fp32)
  gemm256_kernel<<<dim3((S / 256) * (C / 256) * N), 512, 0, stream>>>(
      Wo, C, 0, H2T, C, SC, d_out, S, SC, 1, bo, 1, 1.f, x, C,
      S / 256, C / 256);
}

// Round 5
// 215.028 us; speedup vs baseline: 1.2997x; 1.2690x over previous
//
#include <hip/hip_runtime.h>

#define GROUPS 32
#define EPS 1e-5f

typedef unsigned short u16;
typedef __bf16 bf16x8 __attribute__((ext_vector_type(8)));
typedef float f32x4 __attribute__((ext_vector_type(4)));

__device__ __forceinline__ u16 f2bf(float f) {
  unsigned x = __builtin_bit_cast(unsigned, f);
  x += 0x7FFFu + ((x >> 16) & 1u);
  return (u16)(x >> 16);
}
__device__ __forceinline__ float bf2f(u16 u) {
  unsigned x = ((unsigned)u) << 16;
  return __builtin_bit_cast(float, x);
}

__device__ __forceinline__ void gload_lds16(const void* g, void* l) {
  __builtin_amdgcn_global_load_lds(
      (const __attribute__((address_space(1))) void*)g,
      (__attribute__((address_space(3))) void*)l, 16, 0, 0);
}

// ---------------- weight fp32 -> bf16 (all 4 weights, one dispatch) --------
__global__ __launch_bounds__(256) void cvt_kernel(
    const float* __restrict__ wq, const float* __restrict__ wk,
    const float* __restrict__ wv, const float* __restrict__ wo,
    u16* __restrict__ Wqk, u16* __restrict__ Wv, u16* __restrict__ Wo,
    int n) {
  int i = (blockIdx.x * 256 + threadIdx.x) * 4;
  if (i >= n) return;
  const float* src;
  u16* dst;
  switch (blockIdx.y) {
    case 0: src = wq; dst = Wqk; break;
    case 1: src = wk; dst = Wqk + n; break;
    case 2: src = wv; dst = Wv; break;
    default: src = wo; dst = Wo; break;
  }
  float4 v = *(const float4*)&src[i];
  ushort4 o;
  o.x = f2bf(v.x); o.y = f2bf(v.y); o.z = f2bf(v.z); o.w = f2bf(v.w);
  *(ushort4*)&dst[i] = o;
}

// ---------------- bias concat bq||bk -> fp32[1024] ----------------
__global__ __launch_bounds__(256) void biascat_kernel(
    const float* __restrict__ bq, const float* __restrict__ bk,
    float* __restrict__ bqk, int C) {
  int i = blockIdx.x * 256 + threadIdx.x;
  if (i < C) bqk[i] = bq[i];
  else if (i < 2 * C) bqk[i] = bk[i - C];
}

// ---------------- GroupNorm -> HT [N, S, C] bf16 ----------------
__global__ __launch_bounds__(256) void groupnorm_kernel(
    const float* __restrict__ x, const float* __restrict__ gamma,
    const float* __restrict__ beta, u16* __restrict__ HT, int C, int S) {
  const int cpg = C / GROUPS;  // 16
  int n = blockIdx.x / GROUPS;
  int g = blockIdx.x % GROUPS;
  const float* xb = x + ((size_t)n * C + (size_t)g * cpg) * S;
  int tid = threadIdx.x;
  int cnt = cpg * S;  // 16384
  float s = 0.f, ss = 0.f;
  for (int i = tid * 4; i < cnt; i += 256 * 4) {
    float4 v = *(const float4*)&xb[i];
    s += v.x + v.y + v.z + v.w;
    ss += v.x * v.x + v.y * v.y + v.z * v.z + v.w * v.w;
  }
  for (int o = 32; o > 0; o >>= 1) {
    s += __shfl_xor(s, o);
    ss += __shfl_xor(ss, o);
  }
  __shared__ float rs[4], rss[4];
  int wave = tid >> 6, lane = tid & 63;
  if (lane == 0) { rs[wave] = s; rss[wave] = ss; }
  __syncthreads();
  float S1 = rs[0] + rs[1] + rs[2] + rs[3];
  float S2 = rss[0] + rss[1] + rss[2] + rss[3];
  float mean = S1 / (float)cnt;
  float var = S2 / (float)cnt - mean * mean;
  float rstd = rsqrtf(var + EPS);
  float gm[16], bt[16];
#pragma unroll
  for (int c = 0; c < 16; ++c) {
    float gmv = gamma[g * cpg + c] * rstd;
    gm[c] = gmv;
    bt[c] = beta[g * cpg + c] - mean * gmv;
  }
  for (int i = 0; i < S; i += 256) {
    int sp = i + tid;
    u16 outv[16];
#pragma unroll
    for (int c = 0; c < 16; ++c) {
      float h = xb[(size_t)c * S + sp] * gm[c] + bt[c];
      outv[c] = f2bf(h);
    }
    u16* dst = HT + ((size_t)n * S + sp) * C + g * cpg;
    *(int4*)dst = *(int4*)&outv[0];
    *(int4*)&dst[8] = *(int4*)&outv[8];
  }
}

// =================== 128x128x64 2-phase GEMM (4 waves) =====================
// Out[m][n] = scale*sum_k A[m][k]*B[n][k] (+bias/residual)
// m230-template at 128^2: per K-tile { STAGE(next buf) first; compute current
// (2 k-halves x 16 MFMA/wave); vmcnt(0); s_barrier }. Double-buffered,
// 64 KB LDS total -> 2 blocks/CU resident (cross-block overlap hides drains).
// Row = 64 bf16 = 8 x 16B slots; physical slot p holds global slot p^(row&7).
__global__ __launch_bounds__(256, 2) void gemm128_kernel(
    const u16* __restrict__ A, long lda, long strideA,
    const u16* __restrict__ B, long ldb, long strideB,
    void* __restrict__ Out, long ldo, long strideO, int out_fp32,
    const float* __restrict__ bias, int bias_mode,  // 0 none, 1 row, 2 col
    float scale, const float* __restrict__ residual, int K, int nbx, int nby) {
  __shared__ u16 lds[32768];  // 64 KiB
  u16* As0 = lds;
  u16* As1 = lds + 8192;
  u16* Bs0 = lds + 16384;
  u16* Bs1 = lds + 24576;

  int tid = threadIdx.x;
  int wave = tid >> 6, lane = tid & 63;
  int wr = wave >> 1, wc = wave & 1;
  int l15 = lane & 15, l4 = lane >> 4;

  int nwg = gridDim.x;
  int orig = blockIdx.x;
  int swz = ((nwg & 7) == 0) ? (orig & 7) * (nwg >> 3) + (orig >> 3) : orig;
  int tilesPB = nbx * nby;
  int z = swz / tilesPB, rem = swz % tilesPB;
  int bx = rem % nbx, by = rem / nbx;

  const u16* Ab = A + (long)z * strideA + (long)by * 128 * lda;
  const u16* Bb = B + (long)z * strideB + (long)bx * 128 * ldb;

  // stage one 128x64 tile of A and B each into (Ad, Bd)
  auto STAGE = [&](u16* Ad, u16* Bd, int kt) {
#pragma unroll
    for (int i = 0; i < 4; ++i) {
      int c = i * 256 + tid;          // 0..1023 16B chunks
      int row = c >> 3, p = c & 7;
      int gsl = p ^ (row & 7);        // inverse swizzle on global source
      long koff = (long)kt * 64 + gsl * 8;
      int lbase = (i * 256 + wave * 64) * 8;  // wave-uniform LDS base (elems)
      gload_lds16(Ab + (long)row * lda + koff, Ad + lbase);
      gload_lds16(Bb + (long)row * ldb + koff, Bd + lbase);
    }
  };

  f32x4 acc[4][4] = {};

  auto COMPUTE = [&](const u16* Asrc, const u16* Bsrc) {
#pragma unroll
    for (int kh = 0; kh < 2; ++kh) {
      bf16x8 af[4], bfr[4];
#pragma unroll
      for (int m = 0; m < 4; ++m) {
        int row = wr * 64 + m * 16 + l15;
        int p = (kh * 4 + l4) ^ (row & 7);
        af[m] = *(const bf16x8*)&Asrc[row * 64 + p * 8];
      }
#pragma unroll
      for (int n = 0; n < 4; ++n) {
        int row = wc * 64 + n * 16 + l15;
        int p = (kh * 4 + l4) ^ (row & 7);
        bfr[n] = *(const bf16x8*)&Bsrc[row * 64 + p * 8];
      }
#pragma unroll
      for (int m = 0; m < 4; ++m)
#pragma unroll
        for (int n = 0; n < 4; ++n)
          acc[m][n] = __builtin_amdgcn_mfma_f32_16x16x32_bf16(
              af[m], bfr[n], acc[m][n], 0, 0, 0);
    }
  };

  int NT = K >> 6;
  u16 *Ar = As0, *Br = Bs0, *Aw = As1, *Bw = Bs1;

  STAGE(Ar, Br, 0);
  asm volatile("s_waitcnt vmcnt(0)" ::: "memory");
  __builtin_amdgcn_sched_barrier(0);
  __builtin_amdgcn_s_barrier();
  __builtin_amdgcn_sched_barrier(0);

  for (int t = 0; t < NT - 1; ++t) {
    STAGE(Aw, Bw, t + 1);       // issue next-tile loads first
    COMPUTE(Ar, Br);            // they fly under ds_read + MFMA
    asm volatile("s_waitcnt vmcnt(0)" ::: "memory");
    __builtin_amdgcn_sched_barrier(0);
    __builtin_amdgcn_s_barrier();
    __builtin_amdgcn_sched_barrier(0);
    u16* tp;
    tp = Ar; Ar = Aw; Aw = tp;
    tp = Br; Br = Bw; Bw = tp;
  }
  COMPUTE(Ar, Br);

  long orow0 = (long)by * 128 + wr * 64;
  long ocol0 = (long)bx * 128 + wc * 64;
#pragma unroll
  for (int m = 0; m < 4; ++m) {
#pragma unroll
    for (int n = 0; n < 4; ++n) {
#pragma unroll
      for (int r = 0; r < 4; ++r) {
        long row = orow0 + m * 16 + l4 * 4 + r;
        long col = ocol0 + n * 16 + l15;
        float v = acc[m][n][r] * scale;
        if (bias_mode == 1) v += bias[row];
        else if (bias_mode == 2) v += bias[col];
        long off = (long)z * strideO + row * ldo + col;
        if (residual) v += residual[off];
        if (out_fp32) ((float*)Out)[off] = v;
        else ((u16*)Out)[off] = f2bf(v);
      }
    }
  }
}

// ---------------- softmax over rows of P [rows, S] bf16, in place ----------
__global__ __launch_bounds__(256) void softmax_kernel(u16* __restrict__ P, int S) {
  size_t row = blockIdx.x;
  u16* p = P + row * (size_t)S;
  int tid = threadIdx.x;
  ushort4 u = *(const ushort4*)&p[tid * 4];
  float v0 = bf2f(u.x), v1 = bf2f(u.y), v2 = bf2f(u.z), v3 = bf2f(u.w);
  float m = fmaxf(fmaxf(v0, v1), fmaxf(v2, v3));
  for (int o = 32; o > 0; o >>= 1) m = fmaxf(m, __shfl_xor(m, o));
  __shared__ float redm[4], reds[4];
  int wave = tid >> 6, lane = tid & 63;
  if (lane == 0) redm[wave] = m;
  __syncthreads();
  m = fmaxf(fmaxf(redm[0], redm[1]), fmaxf(redm[2], redm[3]));
  float e0 = __expf(v0 - m), e1 = __expf(v1 - m);
  float e2 = __expf(v2 - m), e3 = __expf(v3 - m);
  float s = e0 + e1 + e2 + e3;
  for (int o = 32; o > 0; o >>= 1) s += __shfl_xor(s, o);
  if (lane == 0) reds[wave] = s;
  __syncthreads();
  s = reds[0] + reds[1] + reds[2] + reds[3];
  float inv = 1.f / s;
  ushort4 o4;
  o4.x = f2bf(e0 * inv); o4.y = f2bf(e1 * inv);
  o4.z = f2bf(e2 * inv); o4.w = f2bf(e3 * inv);
  *(ushort4*)&p[tid * 4] = o4;
}

extern "C" void kernel_launch(void* const* d_in, const int* in_sizes, int n_in,
                              void* d_out, int out_size, void* d_ws, size_t ws_size,
                              hipStream_t stream) {
  const float* x = (const float*)d_in[0];
  const float* gamma = (const float*)d_in[1];
  const float* beta = (const float*)d_in[2];
  const float* wq = (const float*)d_in[3];
  const float* bq = (const float*)d_in[4];
  const float* wk = (const float*)d_in[5];
  const float* bk = (const float*)d_in[6];
  const float* wv = (const float*)d_in[7];
  const float* bv = (const float*)d_in[8];
  const float* wo = (const float*)d_in[9];
  const float* bo = (const float*)d_in[10];

  const int C = 512, S = 1024;
  const int N = in_sizes[0] / (C * S);  // 16
  const long SC = (long)S * C;
  const long S2C = (long)S * 2 * C;
  const long SS = (long)S * S;
  const int CC = C * C;

  char* ws = (char*)d_ws;
  const size_t MB = 1024 * 1024;
  u16* HT = (u16*)(ws + 0 * MB);      // [N,S,C]
  u16* QKT = (u16*)(ws + 16 * MB);    // [N,S,2C]: cols 0..C-1 = Q, C..2C-1 = K
  u16* Vb = (u16*)(ws + 48 * MB);     // [N,C,S]
  u16* P = (u16*)(ws + 64 * MB);      // [N,S,S]
  u16* Wqk = (u16*)(ws + 96 * MB);    // [2C,C]
  u16* Wv = Wqk + 2 * CC;
  u16* Wo = Wv + CC;
  float* bqk = (float*)(Wo + CC);     // [2C]
  u16* H2T = HT;                      // overlay: HT dead after V-GEMM

  cvt_kernel<<<dim3(CC / 1024, 4), 256, 0, stream>>>(wq, wk, wv, wo, Wqk, Wv, Wo, CC);
  biascat_kernel<<<4, 256, 0, stream>>>(bq, bk, bqk, C);
  groupnorm_kernel<<<N * GROUPS, 256, 0, stream>>>(x, gamma, beta, HT, C, S);

  const float scl = 1.0f / sqrtf((float)C);

  // fused Q,K projection: QKT[s][j] = sum_c HT[s][c]*Wqk[j][c] + bqk[j]
  gemm128_kernel<<<dim3((2 * C / 128) * (S / 128) * N), 256, 0, stream>>>(
      HT, C, SC, Wqk, C, 0, QKT, 2 * C, S2C, 0, bqk, 2, 1.f, nullptr, C,
      2 * C / 128, S / 128);
  // V[c][s] = sum_k Wv[c][k]*HT[s][k] + bv[c]
  gemm128_kernel<<<dim3((S / 128) * (C / 128) * N), 256, 0, stream>>>(
      Wv, C, 0, HT, C, SC, Vb, S, SC, 0, bv, 1, 1.f, nullptr, C,
      S / 128, C / 128);
  // P[s][t] = scl * sum_c Q[s][c]*K[t][c]
  gemm128_kernel<<<dim3((S / 128) * (S / 128) * N), 256, 0, stream>>>(
      QKT, 2 * C, S2C, QKT + C, 2 * C, S2C, P, S, SS, 0, nullptr, 0, scl,
      nullptr, C, S / 128, S / 128);
  softmax_kernel<<<N * S, 256, 0, stream>>>(P, S);
  // H2T[s][c] = sum_t P[s][t]*V[c][t]
  gemm128_kernel<<<dim3((C / 128) * (S / 128) * N), 256, 0, stream>>>(
      P, S, SS, Vb, S, SC, H2T, C, SC, 0, nullptr, 0, 1.f, nullptr, S,
      C / 128, S / 128);
  // out[c][s] = x + bo[c] + sum_k Wo[c][k]*H2T[s][k]   (fp32)
  gemm128_kernel<<<dim3((S / 128) * (C / 128) * N), 256, 0, stream>>>(
      Wo, C, 0, H2T, C, SC, d_out, S, SC, 1, bo, 1, 1.f, x, C,
      S / 128, C / 128);
}